// Round 2
// baseline (302.455 us; speedup 1.0000x reference)
//
#include <hip/hip_runtime.h>
#include <math.h>

#define NB 16
#define NH 128
#define NP 64
#define NL 8192

// ---------------- K1: Bu[b,p,l] = sum_h B[p,h] * u[b,h,l] (B complex, u real) ----
// grid (NL/128, NB), block 256. ws layout: float2 bu[(b*64+p)*8192 + l]
__global__ __launch_bounds__(256) void k_bu(
    const float* __restrict__ u, const float* __restrict__ Bre,
    const float* __restrict__ Bim, float2* __restrict__ bu) {
  __shared__ float sBre[32][68];   // [h][p], padded (transpose-write conflicts)
  __shared__ float sBim[32][68];
  __shared__ float sU[32][128];    // [h][l]
  const int b  = blockIdx.y;
  const int l0 = blockIdx.x * 128;
  const int t  = threadIdx.x;
  const int tp = t & 15;           // p-group: p = tp*4 + i
  const int tl = t >> 4;           // l-group: l = tl*8 + j
  float accRe[4][8], accIm[4][8];
  #pragma unroll
  for (int i = 0; i < 4; ++i)
    #pragma unroll
    for (int j = 0; j < 8; ++j) { accRe[i][j] = 0.f; accIm[i][j] = 0.f; }

  for (int ht = 0; ht < 4; ++ht) {
    const int h0 = ht * 32;
    // load B tile: h fastest -> coalesced global rows of 32
    #pragma unroll
    for (int idx = t; idx < 2048; idx += 256) {
      int h = idx & 31, p = idx >> 5;
      sBre[h][p] = Bre[p * NH + h0 + h];
      sBim[h][p] = Bim[p * NH + h0 + h];
    }
    // load u tile: l fastest -> coalesced
    #pragma unroll
    for (int idx = t; idx < 32 * 128; idx += 256) {
      int l = idx & 127, h = idx >> 7;
      sU[h][l] = u[((size_t)(b * NH + h0 + h)) * NL + l0 + l];
    }
    __syncthreads();
    #pragma unroll 4
    for (int h = 0; h < 32; ++h) {
      float4 br4 = *(const float4*)&sBre[h][tp * 4];
      float4 bi4 = *(const float4*)&sBim[h][tp * 4];
      float4 ua  = *(const float4*)&sU[h][tl * 8];
      float4 ub  = *(const float4*)&sU[h][tl * 8 + 4];
      float uu[8] = {ua.x, ua.y, ua.z, ua.w, ub.x, ub.y, ub.z, ub.w};
      float brr[4] = {br4.x, br4.y, br4.z, br4.w};
      float bii[4] = {bi4.x, bi4.y, bi4.z, bi4.w};
      #pragma unroll
      for (int i = 0; i < 4; ++i)
        #pragma unroll
        for (int j = 0; j < 8; ++j) {
          accRe[i][j] = fmaf(brr[i], uu[j], accRe[i][j]);
          accIm[i][j] = fmaf(bii[i], uu[j], accIm[i][j]);
        }
    }
    __syncthreads();
  }
  #pragma unroll
  for (int i = 0; i < 4; ++i) {
    size_t base = ((size_t)(b * NP + tp * 4 + i)) * NL + l0 + tl * 8;
    #pragma unroll
    for (int j = 0; j < 8; j += 2) {
      float4 v = make_float4(accRe[i][j], accIm[i][j], accRe[i][j + 1], accIm[i][j + 1]);
      *(float4*)&bu[base + j] = v;
    }
  }
}

// ---------------- K2: in-place inclusive scan x[l] = Lam*x[l-1] + bu[l] --------
// grid NB*NP blocks, 256 threads; each thread owns a contiguous chunk of 32.
__global__ __launch_bounds__(256) void k_scan(
    float2* __restrict__ bu, const float* __restrict__ Lre,
    const float* __restrict__ Lim) {
  extern __shared__ float2 s[];    // 8448 float2 = 67584 B (padded transpose buf)
  const int bp = blockIdx.x;
  const int p  = bp & (NP - 1);
  const int t  = threadIdx.x;
  const size_t base = (size_t)bp * NL;

  float2 v[32];
  // coalesced load, strided-per-thread
  #pragma unroll
  for (int j = 0; j < 32; ++j) v[j] = bu[base + t + 256 * j];
  // transpose to contiguous chunks via padded LDS
  #pragma unroll
  for (int j = 0; j < 32; ++j) { int i = t + 256 * j; s[i + (i >> 5)] = v[j]; }
  __syncthreads();
  #pragma unroll
  for (int j = 0; j < 32; ++j) v[j] = s[t * 33 + j];

  const float lr = Lre[p], li = Lim[p];
  // local serial inclusive scan of the chunk
  float xr = 0.f, xi = 0.f;
  #pragma unroll
  for (int j = 0; j < 32; ++j) {
    float nr = fmaf(lr, xr, fmaf(-li, xi, v[j].x));
    float ni = fmaf(lr, xi, fmaf( li, xr, v[j].y));
    xr = nr; xi = ni;
    v[j].x = xr; v[j].y = xi;
  }
  __syncthreads();   // chunk reads done; reuse s[0..255] for totals

  // cross-thread scan of chunk totals with constant factor Lam^32
  float wr = lr, wi = li;
  #pragma unroll
  for (int k = 0; k < 5; ++k) { float nr = wr * wr - wi * wi; wi = 2.f * wr * wi; wr = nr; }
  float2 tot = v[31];
  s[t] = tot;
  __syncthreads();
  for (int d = 1; d < 256; d <<= 1) {
    float2 nb;
    if (t >= d) nb = s[t - d];
    __syncthreads();
    if (t >= d) {
      tot.x += wr * nb.x - wi * nb.y;
      tot.y += wr * nb.y + wi * nb.x;
      s[t] = tot;
    }
    __syncthreads();
    float nr = wr * wr - wi * wi; wi = 2.f * wr * wi; wr = nr;
  }
  float2 ep = (t > 0) ? s[t - 1] : make_float2(0.f, 0.f);
  __syncthreads();   // totals reads done before big-buffer reuse

  // apply carry: x[j] += Lam^{j+1} * E_prev
  float cr = ep.x, ci = ep.y;
  #pragma unroll
  for (int j = 0; j < 32; ++j) {
    float nr = lr * cr - li * ci;
    float nc = lr * ci + li * cr;
    cr = nr; ci = nc;
    v[j].x += cr; v[j].y += ci;
  }
  // transpose back and coalesced store
  #pragma unroll
  for (int j = 0; j < 32; ++j) s[t * 33 + j] = v[j];
  __syncthreads();
  #pragma unroll
  for (int j = 0; j < 32; ++j) { int i = t + 256 * j; bu[base + i] = s[i + (i >> 5)]; }
}

// ---------------- K3: out = gelu( Re(C @ x) + diag(D)*u ) ----------------------
// grid (NL/128, NB), block 256
__global__ __launch_bounds__(256) void k_out(
    const float2* __restrict__ xs, const float* __restrict__ u,
    const float* __restrict__ Cre, const float* __restrict__ Cim,
    const float* __restrict__ D, float* __restrict__ out) {
  __shared__ float sCre[16][132];  // [p][h], padded
  __shared__ float sCim[16][132];
  __shared__ float sXre[16][128];  // [p][l]
  __shared__ float sXim[16][128];
  __shared__ float sDd[128];
  const int b  = blockIdx.y;
  const int l0 = blockIdx.x * 128;
  const int t  = threadIdx.x;
  const int lane = t & 63, w = t >> 6;
  const int th = (lane & 7) + 8 * (w & 1);    // h-group: h = th*8 + i
  const int tl = (lane >> 3) + 8 * (w >> 1);  // l-group: l = tl*8 + j

  if (t < 128) sDd[t] = D[t * NH + t];

  float acc[8][8];
  #pragma unroll
  for (int i = 0; i < 8; ++i)
    #pragma unroll
    for (int j = 0; j < 8; ++j) acc[i][j] = 0.f;

  for (int pt = 0; pt < 4; ++pt) {
    const int p0 = pt * 16;
    __syncthreads();   // protect LDS reuse across iterations (and sDd on first)
    #pragma unroll
    for (int idx = t; idx < 2048; idx += 256) {
      int pp = idx & 15, h = idx >> 4;
      sCre[pp][h] = Cre[h * NP + p0 + pp];
      sCim[pp][h] = Cim[h * NP + p0 + pp];
    }
    #pragma unroll
    for (int idx = t; idx < 2048; idx += 256) {
      int l = idx & 127, pp = idx >> 7;
      float2 xv = xs[((size_t)(b * NP + p0 + pp)) * NL + l0 + l];
      sXre[pp][l] = xv.x; sXim[pp][l] = xv.y;
    }
    __syncthreads();
    #pragma unroll 4
    for (int pp = 0; pp < 16; ++pp) {
      float4 ca = *(const float4*)&sCre[pp][th * 8];
      float4 cb = *(const float4*)&sCre[pp][th * 8 + 4];
      float4 ia = *(const float4*)&sCim[pp][th * 8];
      float4 ib = *(const float4*)&sCim[pp][th * 8 + 4];
      float4 xa = *(const float4*)&sXre[pp][tl * 8];
      float4 xb = *(const float4*)&sXre[pp][tl * 8 + 4];
      float4 ya = *(const float4*)&sXim[pp][tl * 8];
      float4 yb = *(const float4*)&sXim[pp][tl * 8 + 4];
      float cr[8] = {ca.x, ca.y, ca.z, ca.w, cb.x, cb.y, cb.z, cb.w};
      float ci[8] = {ia.x, ia.y, ia.z, ia.w, ib.x, ib.y, ib.z, ib.w};
      float xr[8] = {xa.x, xa.y, xa.z, xa.w, xb.x, xb.y, xb.z, xb.w};
      float xi[8] = {ya.x, ya.y, ya.z, ya.w, yb.x, yb.y, yb.z, yb.w};
      #pragma unroll
      for (int i = 0; i < 8; ++i)
        #pragma unroll
        for (int j = 0; j < 8; ++j) {
          acc[i][j] = fmaf(cr[i], xr[j], acc[i][j]);
          acc[i][j] = fmaf(-ci[i], xi[j], acc[i][j]);
        }
    }
  }

  // epilogue: + diag(D)*u, exact gelu, store
  #pragma unroll
  for (int i = 0; i < 8; ++i) {
    const int h = th * 8 + i;
    const float dd = sDd[h];
    size_t rb = ((size_t)(b * NH + h)) * NL + l0 + tl * 8;
    float4 u0 = *(const float4*)&u[rb];
    float4 u1 = *(const float4*)&u[rb + 4];
    float uu[8] = {u0.x, u0.y, u0.z, u0.w, u1.x, u1.y, u1.z, u1.w};
    float r[8];
    #pragma unroll
    for (int j = 0; j < 8; ++j) {
      float vv = acc[i][j] + dd * uu[j];
      r[j] = 0.5f * vv * (1.0f + erff(vv * 0.70710678118654752f));
    }
    *(float4*)&out[rb]     = make_float4(r[0], r[1], r[2], r[3]);
    *(float4*)&out[rb + 4] = make_float4(r[4], r[5], r[6], r[7]);
  }
}

extern "C" void kernel_launch(void* const* d_in, const int* in_sizes, int n_in,
                              void* d_out, int out_size, void* d_ws, size_t ws_size,
                              hipStream_t stream) {
  (void)in_sizes; (void)n_in; (void)out_size; (void)ws_size;
  const float* u   = (const float*)d_in[0];
  const float* Lre = (const float*)d_in[1];
  const float* Lim = (const float*)d_in[2];
  const float* Bre = (const float*)d_in[3];
  const float* Bim = (const float*)d_in[4];
  const float* Cre = (const float*)d_in[5];
  const float* Cim = (const float*)d_in[6];
  const float* Dm  = (const float*)d_in[7];
  float* out = (float*)d_out;
  float2* bu = (float2*)d_ws;   // needs NB*NP*NL*8 = 64 MiB

  dim3 g1(NL / 128, NB);
  k_bu<<<g1, 256, 0, stream>>>(u, Bre, Bim, bu);
  k_scan<<<NB * NP, 256, 8448 * sizeof(float2), stream>>>(bu, Lre, Lim);
  dim3 g3(NL / 128, NB);
  k_out<<<g3, 256, 0, stream>>>(bu, u, Cre, Cim, Dm, out);
}

// Round 6
// 264.041 us; speedup vs baseline: 1.1455x; 1.1455x over previous
//
#include <hip/hip_runtime.h>
#include <math.h>

#define NB 16
#define NH 128
#define NP 64
#define NL 8192
#define NCHUNK 64   // NL / 128

// ---- K1: Bu = B@u fused with chunk-local scan over the 128-l tile ------------
// grid (64, 16), block 256. Writes x_local (chunk-scanned, zero-init) and
// per-chunk totals Echunk[b][c][p].
__global__ __launch_bounds__(256) void k_bu_scan(
    const float* __restrict__ u, const float* __restrict__ Bre,
    const float* __restrict__ Bim, const float* __restrict__ Lre,
    const float* __restrict__ Lim, float2* __restrict__ xloc,
    float2* __restrict__ Echunk) {
  __shared__ __align__(16) float sBre[32][68];   // [h][p], padded; reused as E later
  __shared__ float sBim[32][68];
  __shared__ float sU[32][128];
  const int b  = blockIdx.y;
  const int c  = blockIdx.x;        // l-chunk
  const int l0 = c * 128;
  const int t  = threadIdx.x;
  const int tp = t & 15;            // p = tp*4 + i
  const int tl = t >> 4;            // l = l0 + tl*8 + j
  float accRe[4][8], accIm[4][8];
  #pragma unroll
  for (int i = 0; i < 4; ++i)
    #pragma unroll
    for (int j = 0; j < 8; ++j) { accRe[i][j] = 0.f; accIm[i][j] = 0.f; }

  for (int ht = 0; ht < 4; ++ht) {
    const int h0 = ht * 32;
    #pragma unroll
    for (int idx = t; idx < 2048; idx += 256) {
      int h = idx & 31, p = idx >> 5;
      sBre[h][p] = Bre[p * NH + h0 + h];
      sBim[h][p] = Bim[p * NH + h0 + h];
    }
    #pragma unroll
    for (int idx = t; idx < 32 * 128; idx += 256) {
      int l = idx & 127, h = idx >> 7;
      sU[h][l] = u[((size_t)(b * NH + h0 + h)) * NL + l0 + l];
    }
    __syncthreads();
    #pragma unroll 4
    for (int h = 0; h < 32; ++h) {
      float4 br4 = *(const float4*)&sBre[h][tp * 4];
      float4 bi4 = *(const float4*)&sBim[h][tp * 4];
      float4 ua  = *(const float4*)&sU[h][tl * 8];
      float4 ub  = *(const float4*)&sU[h][tl * 8 + 4];
      float uu[8] = {ua.x, ua.y, ua.z, ua.w, ub.x, ub.y, ub.z, ub.w};
      float brr[4] = {br4.x, br4.y, br4.z, br4.w};
      float bii[4] = {bi4.x, bi4.y, bi4.z, bi4.w};
      #pragma unroll
      for (int i = 0; i < 4; ++i)
        #pragma unroll
        for (int j = 0; j < 8; ++j) {
          accRe[i][j] = fmaf(brr[i], uu[j], accRe[i][j]);
          accIm[i][j] = fmaf(bii[i], uu[j], accIm[i][j]);
        }
    }
    __syncthreads();   // also guarantees sBre free for reuse after the loop
  }

  // ---- local scan over this thread's 8 contiguous l (zero initial state) ----
  float lr[4], li[4];
  #pragma unroll
  for (int i = 0; i < 4; ++i) { lr[i] = Lre[tp * 4 + i]; li[i] = Lim[tp * 4 + i]; }
  #pragma unroll
  for (int i = 0; i < 4; ++i) {
    float xr = 0.f, xi = 0.f;
    #pragma unroll
    for (int j = 0; j < 8; ++j) {
      float nr = fmaf(lr[i], xr, fmaf(-li[i], xi, accRe[i][j]));
      float ni = fmaf(lr[i], xi, fmaf( li[i], xr, accIm[i][j]));
      xr = nr; xi = ni; accRe[i][j] = xr; accIm[i][j] = xi;
    }
  }

  // ---- Hillis scan over the 16 sub-chunks (factor Lam^8), in LDS ------------
  float2* E = reinterpret_cast<float2*>(&sBre[0][0]);  // 64*17 float2 = 8704 B, fits exactly
  #define EL(p, q) E[(p) * 17 + (q)]
  #pragma unroll
  for (int i = 0; i < 4; ++i)
    EL(tp * 4 + i, tl) = make_float2(accRe[i][7], accIm[i][7]);

  float wr[4], wi[4];  // Lam^8 per i, then squared each Hillis step
  #pragma unroll
  for (int i = 0; i < 4; ++i) {
    float ar = lr[i], ai = li[i];
    #pragma unroll
    for (int k = 0; k < 3; ++k) { float nr = ar * ar - ai * ai; ai = 2.f * ar * ai; ar = nr; }
    wr[i] = ar; wi[i] = ai;
  }
  __syncthreads();
  #pragma unroll
  for (int d = 1; d < 16; d <<= 1) {
    float2 rv[4];
    #pragma unroll
    for (int i = 0; i < 4; ++i)
      rv[i] = (tl >= d) ? EL(tp * 4 + i, tl - d) : make_float2(0.f, 0.f);
    __syncthreads();
    if (tl >= d) {
      #pragma unroll
      for (int i = 0; i < 4; ++i) {
        float2 cur = EL(tp * 4 + i, tl);
        cur.x += wr[i] * rv[i].x - wi[i] * rv[i].y;
        cur.y += wr[i] * rv[i].y + wi[i] * rv[i].x;
        EL(tp * 4 + i, tl) = cur;
      }
    }
    __syncthreads();
    #pragma unroll
    for (int i = 0; i < 4; ++i) {
      float nr = wr[i] * wr[i] - wi[i] * wi[i];
      wi[i] = 2.f * wr[i] * wi[i]; wr[i] = nr;
    }
  }

  // incoming state for this thread's sub-chunk, chunk total to global
  float2 cin[4];
  #pragma unroll
  for (int i = 0; i < 4; ++i)
    cin[i] = (tl > 0) ? EL(tp * 4 + i, tl - 1) : make_float2(0.f, 0.f);
  if (t < 64) {
    float2 tot = EL(t, 15);
    Echunk[((size_t)(b * NCHUNK + c)) * NP + t] = tot;
  }

  // apply sub-chunk carry: x_j += Lam^{j+1} * cin
  #pragma unroll
  for (int i = 0; i < 4; ++i) {
    float cr = cin[i].x, ci = cin[i].y;
    #pragma unroll
    for (int j = 0; j < 8; ++j) {
      float nr = lr[i] * cr - li[i] * ci;
      float nc = lr[i] * ci + li[i] * cr;
      cr = nr; ci = nc;
      accRe[i][j] += cr; accIm[i][j] += ci;
    }
  }

  // store x_local
  #pragma unroll
  for (int i = 0; i < 4; ++i) {
    size_t base = ((size_t)(b * NP + tp * 4 + i)) * NL + l0 + tl * 8;
    #pragma unroll
    for (int j = 0; j < 8; j += 2) {
      float4 v = make_float4(accRe[i][j], accIm[i][j], accRe[i][j + 1], accIm[i][j + 1]);
      *(float4*)&xloc[base + j] = v;
    }
  }
  #undef EL
}

// ---- K2: scan chunk totals (factor Lam^128) -> per-chunk incoming carries; ---
// also emit pow table Lam^{j+1}. grid 16 blocks (b), 64 threads (p).
__global__ void k_carry(const float2* __restrict__ Echunk,
                        const float* __restrict__ Lre, const float* __restrict__ Lim,
                        float2* __restrict__ carryg, float2* __restrict__ powtab) {
  const int b = blockIdx.x, p = threadIdx.x;
  const float lr = Lre[p], li = Lim[p];
  float wr = lr, wi = li;          // -> Lam^128 via 7 squarings
  #pragma unroll
  for (int k = 0; k < 7; ++k) { float nr = wr * wr - wi * wi; wi = 2.f * wr * wi; wr = nr; }
  float xr = 0.f, xi = 0.f;
  for (int c = 0; c < NCHUNK; ++c) {
    carryg[((size_t)(b * NCHUNK + c)) * NP + p] = make_float2(xr, xi);
    float2 e = Echunk[((size_t)(b * NCHUNK + c)) * NP + p];
    float nr = e.x + wr * xr - wi * xi;
    float ni = e.y + wr * xi + wi * xr;
    xr = nr; xi = ni;
  }
  if (b == 0) {
    float pr = 1.f, pi = 0.f;
    for (int j = 0; j < 128; ++j) {
      float nr = pr * lr - pi * li;
      pi = pr * li + pi * lr; pr = nr;
      powtab[p * 128 + j] = make_float2(pr, pi);   // Lam^{j+1}
    }
  }
}

// ---- K3: out = gelu( Re(C @ (xloc + Lam^{j+1}*carry)) + diag(D)*u ) ----------
// grid (64, 16), block 256; x-tile loads software-pipelined through registers.
__global__ __launch_bounds__(256) void k_out(
    const float2* __restrict__ xs, const float* __restrict__ u,
    const float* __restrict__ Cre, const float* __restrict__ Cim,
    const float* __restrict__ D, const float2* __restrict__ carryg,
    const float2* __restrict__ powtab, float* __restrict__ out) {
  __shared__ float sCre[16][132];
  __shared__ float sCim[16][132];
  __shared__ float sXre[16][128];
  __shared__ float sXim[16][128];
  __shared__ float sDd[128];
  const int b  = blockIdx.y;
  const int c  = blockIdx.x;
  const int l0 = c * 128;
  const int t  = threadIdx.x;
  const int lane = t & 63, w = t >> 6;
  const int th = (lane & 7) + 8 * (w & 1);
  const int tl = (lane >> 3) + 8 * (w >> 1);
  const int lfix = t & 127;        // fixed l for this thread in load loops
  const int ppb  = t >> 7;         // pp parity base

  if (t < 128) sDd[t] = D[t * NH + t];

  float acc[8][8];
  #pragma unroll
  for (int i = 0; i < 8; ++i)
    #pragma unroll
    for (int j = 0; j < 8; ++j) acc[i][j] = 0.f;

  float2 gx[8], gp[8], gc[8];
  // prologue: issue loads for pt = 0
  #pragma unroll
  for (int k = 0; k < 8; ++k) {
    int pp = ppb + 2 * k;
    gx[k] = xs[((size_t)(b * NP + pp)) * NL + l0 + lfix];
    gp[k] = powtab[pp * 128 + lfix];
    gc[k] = carryg[((size_t)(b * NCHUNK + c)) * NP + pp];
  }

  #pragma unroll
  for (int pt = 0; pt < 4; ++pt) {
    const int p0 = pt * 16;
    __syncthreads();   // previous compute done; LDS writable (covers sDd on pt=0)
    // C tile -> LDS
    #pragma unroll
    for (int idx = t; idx < 2048; idx += 256) {
      int pp = idx & 15, h = idx >> 4;
      sCre[pp][h] = Cre[h * NP + p0 + pp];
      sCim[pp][h] = Cim[h * NP + p0 + pp];
    }
    // x tile (regs loaded last iteration) + carry apply -> LDS
    #pragma unroll
    for (int k = 0; k < 8; ++k) {
      int pp = ppb + 2 * k;
      float xr = gx[k].x + gp[k].x * gc[k].x - gp[k].y * gc[k].y;
      float xi = gx[k].y + gp[k].x * gc[k].y + gp[k].y * gc[k].x;
      sXre[pp][lfix] = xr; sXim[pp][lfix] = xi;
    }
    __syncthreads();
    // issue next pt's loads; they complete under the FMA loop below
    if (pt < 3) {
      const int p1 = (pt + 1) * 16;
      #pragma unroll
      for (int k = 0; k < 8; ++k) {
        int pp = ppb + 2 * k;
        gx[k] = xs[((size_t)(b * NP + p1 + pp)) * NL + l0 + lfix];
        gp[k] = powtab[(p1 + pp) * 128 + lfix];
        gc[k] = carryg[((size_t)(b * NCHUNK + c)) * NP + p1 + pp];
      }
    }
    #pragma unroll 4
    for (int pp = 0; pp < 16; ++pp) {
      float4 ca = *(const float4*)&sCre[pp][th * 8];
      float4 cb = *(const float4*)&sCre[pp][th * 8 + 4];
      float4 ia = *(const float4*)&sCim[pp][th * 8];
      float4 ib = *(const float4*)&sCim[pp][th * 8 + 4];
      float4 xa = *(const float4*)&sXre[pp][tl * 8];
      float4 xb = *(const float4*)&sXre[pp][tl * 8 + 4];
      float4 ya = *(const float4*)&sXim[pp][tl * 8];
      float4 yb = *(const float4*)&sXim[pp][tl * 8 + 4];
      float cr[8] = {ca.x, ca.y, ca.z, ca.w, cb.x, cb.y, cb.z, cb.w};
      float ci[8] = {ia.x, ia.y, ia.z, ia.w, ib.x, ib.y, ib.z, ib.w};
      float xr[8] = {xa.x, xa.y, xa.z, xa.w, xb.x, xb.y, xb.z, xb.w};
      float xi[8] = {ya.x, ya.y, ya.z, ya.w, yb.x, yb.y, yb.z, yb.w};
      #pragma unroll
      for (int i = 0; i < 8; ++i)
        #pragma unroll
        for (int j = 0; j < 8; ++j) {
          acc[i][j] = fmaf(cr[i], xr[j], acc[i][j]);
          acc[i][j] = fmaf(-ci[i], xi[j], acc[i][j]);
        }
    }
  }

  #pragma unroll
  for (int i = 0; i < 8; ++i) {
    const int h = th * 8 + i;
    const float dd = sDd[h];
    size_t rb = ((size_t)(b * NH + h)) * NL + l0 + tl * 8;
    float4 u0 = *(const float4*)&u[rb];
    float4 u1 = *(const float4*)&u[rb + 4];
    float uu[8] = {u0.x, u0.y, u0.z, u0.w, u1.x, u1.y, u1.z, u1.w};
    float r[8];
    #pragma unroll
    for (int j = 0; j < 8; ++j) {
      float vv = acc[i][j] + dd * uu[j];
      r[j] = 0.5f * vv * (1.0f + erff(vv * 0.70710678118654752f));
    }
    *(float4*)&out[rb]     = make_float4(r[0], r[1], r[2], r[3]);
    *(float4*)&out[rb + 4] = make_float4(r[4], r[5], r[6], r[7]);
  }
}

extern "C" void kernel_launch(void* const* d_in, const int* in_sizes, int n_in,
                              void* d_out, int out_size, void* d_ws, size_t ws_size,
                              hipStream_t stream) {
  (void)in_sizes; (void)n_in; (void)out_size; (void)ws_size;
  const float* u   = (const float*)d_in[0];
  const float* Lre = (const float*)d_in[1];
  const float* Lim = (const float*)d_in[2];
  const float* Bre = (const float*)d_in[3];
  const float* Bim = (const float*)d_in[4];
  const float* Cre = (const float*)d_in[5];
  const float* Cim = (const float*)d_in[6];
  const float* Dm  = (const float*)d_in[7];
  float* out = (float*)d_out;

  char* wsb = (char*)d_ws;
  float2* xloc   = (float2*)wsb;                              // 64 MiB
  float2* Echunk = (float2*)(wsb + 67108864);                 // 512 KiB
  float2* carryg = (float2*)(wsb + 67108864 + 524288);        // 512 KiB
  float2* powtab = (float2*)(wsb + 67108864 + 1048576);       // 64 KiB

  dim3 g(NL / 128, NB);
  k_bu_scan<<<g, 256, 0, stream>>>(u, Bre, Bim, Lre, Lim, xloc, Echunk);
  k_carry<<<NB, NP, 0, stream>>>(Echunk, Lre, Lim, carryg, powtab);
  k_out<<<g, 256, 0, stream>>>(xloc, u, Cre, Cim, Dm, carryg, powtab, out);
}